// Round 1
// baseline (208.250 us; speedup 1.0000x reference)
//
#include <hip/hip_runtime.h>
#include <math.h>

#define BATCH 2
#define SEQ   2048
#define DM    1024
#define NS    16
#define RK    64
#define NCH   128            // chunks over SEQ
#define CL    (SEQ / NCH)    // 16 steps per chunk

#define LOG2E 1.4426950408889634f

#if __has_builtin(__builtin_amdgcn_exp2f)
__device__ __forceinline__ float fexp2(float x) { return __builtin_amdgcn_exp2f(x); }
#else
__device__ __forceinline__ float fexp2(float x) { return exp2f(x); }
#endif

// ---------------- conv (depthwise, causal, K=4) + SiLU ----------------
__global__ __launch_bounds__(256) void k_conv(const float* __restrict__ x,
    const float* __restrict__ cw, const float* __restrict__ cb,
    float* __restrict__ xc)
{
    int idx = blockIdx.x * 256 + threadIdx.x;        // over B*SEQ*DM
    int d = idx & (DM - 1);
    int l = (idx >> 10) & (SEQ - 1);
    float4 w = *(const float4*)(cw + d * 4);
    float acc = cb[d];
    float x0 = (l >= 3) ? x[idx - 3 * DM] : 0.f;
    float x1 = (l >= 2) ? x[idx - 2 * DM] : 0.f;
    float x2 = (l >= 1) ? x[idx - 1 * DM] : 0.f;
    float x3 = x[idx];
    acc = fmaf(x0, w.x, acc);
    acc = fmaf(x1, w.y, acc);
    acc = fmaf(x2, w.z, acc);
    acc = fmaf(x3, w.w, acc);
    float e = __expf(-acc);
    xc[idx] = acc / (1.f + e);
}

// ---------------- transpose dt_proj_w (DM x RK) -> (RK x DM) ----------------
__global__ __launch_bounds__(256) void k_twdt(const float* __restrict__ w,
                                              float* __restrict__ wt)
{
    int t = blockIdx.x * 256 + threadIdx.x;          // over RK*DM, out idx r*DM+d
    int d = t & (DM - 1);
    int r = t >> 10;
    wt[t] = w[d * RK + r];
}

// ---------------- fused projections: xc(4096x1024) @ [Wdt;Wb;Wc]^T (96x1024) ----------------
__global__ __launch_bounds__(256) void k_proj(const float* __restrict__ xc,
    const float* __restrict__ wx, const float* __restrict__ wb,
    const float* __restrict__ wc, float* __restrict__ dl,
    float* __restrict__ Bs, float* __restrict__ Cs)
{
    __shared__ __align__(16) float row[DM];
    int bl = blockIdx.x;                              // (b,l) flattened
    const float* xr = xc + (size_t)bl * DM;
    ((float4*)row)[threadIdx.x] = ((const float4*)xr)[threadIdx.x];
    __syncthreads();
    int wave = threadIdx.x >> 6;
    int lane = threadIdx.x & 63;
    #pragma unroll 2
    for (int i = 0; i < 24; i++) {
        int r = wave * 24 + i;
        const float* W = (r < 64) ? (wx + (size_t)r * DM)
                       : (r < 80) ? (wb + (size_t)(r - 64) * DM)
                                  : (wc + (size_t)(r - 80) * DM);
        float acc = 0.f;
        #pragma unroll
        for (int c = 0; c < 4; c++) {
            int k = c * 256 + lane * 4;
            float4 wv = *(const float4*)(W + k);
            float4 xv = *(const float4*)(row + k);
            acc = fmaf(wv.x, xv.x, acc);
            acc = fmaf(wv.y, xv.y, acc);
            acc = fmaf(wv.z, xv.z, acc);
            acc = fmaf(wv.w, xv.w, acc);
        }
        #pragma unroll
        for (int off = 32; off; off >>= 1) acc += __shfl_xor(acc, off, 64);
        if (lane == 0) {
            if (r < 64)      dl[(size_t)bl * RK + r] = acc;
            else if (r < 80) Bs[(size_t)bl * NS + (r - 64)] = acc;
            else             Cs[(size_t)bl * NS + (r - 80)] = acc;
        }
    }
}

// ---------------- dt = softplus(dtlow(4096x64) @ WdtT + b) ----------------
__global__ __launch_bounds__(256) void k_dt(const float* __restrict__ dl,
    const float* __restrict__ wt, const float* __restrict__ bias,
    float* __restrict__ dt)
{
    __shared__ __align__(16) float lr[16][RK];
    int tid = threadIdx.x;
    int row0 = blockIdx.y * 16;
    ((float4*)&lr[0][0])[tid] = ((const float4*)(dl + (size_t)row0 * RK))[tid];
    __syncthreads();
    int d = blockIdx.x * 256 + tid;
    float acc[16];
    #pragma unroll
    for (int m = 0; m < 16; m++) acc[m] = 0.f;
    #pragma unroll 4
    for (int r = 0; r < RK; r++) {
        float w = wt[(size_t)r * DM + d];
        #pragma unroll
        for (int m = 0; m < 16; m++) acc[m] = fmaf(lr[m][r], w, acc[m]);
    }
    float b = bias[d];
    #pragma unroll
    for (int m = 0; m < 16; m++) {
        float z = acc[m] + b;
        float e = __expf(-fabsf(z));
        float sp = fmaxf(z, 0.f) + __logf(1.f + e);
        dt[(size_t)(row0 + m) * DM + d] = sp;
    }
}

// ---------------- scan pass 1: chunk-local states + sum(dt) per chunk ----------------
__global__ __launch_bounds__(256) void k_scan1(const float* __restrict__ dt,
    const float* __restrict__ xc, const float* __restrict__ Bs,
    const float* __restrict__ alog, float* __restrict__ S,
    float* __restrict__ sdtA)
{
    int d = blockIdx.x * 256 + threadIdx.x;
    int c = blockIdx.y;
    int b = blockIdx.z;
    float a2[NS], h[NS];
    #pragma unroll
    for (int n = 0; n < NS; n++) {
        a2[n] = -__expf(alog[d * NS + n]) * LOG2E;
        h[n] = 0.f;
    }
    int l0 = c * CL;
    const float* dtp = dt + ((size_t)(b * SEQ + l0)) * DM + d;
    const float* xcp = xc + ((size_t)(b * SEQ + l0)) * DM + d;
    const float* bp  = Bs + ((size_t)(b * SEQ + l0)) * NS;
    float sdt = 0.f;
    #pragma unroll 4
    for (int i = 0; i < CL; i++) {
        float dtv = dtp[(size_t)i * DM];
        float xcv = xcp[(size_t)i * DM];
        float dbx = dtv * xcv;
        sdt += dtv;
        #pragma unroll
        for (int n = 0; n < NS; n++) {
            float e = fexp2(dtv * a2[n]);
            h[n] = fmaf(e, h[n], dbx * bp[i * NS + n]);
        }
    }
    float* sp = S + (((size_t)(b * NCH + c) * DM) + d) * NS;
    #pragma unroll
    for (int n = 0; n < NS; n += 4)
        *(float4*)(sp + n) = make_float4(h[n], h[n + 1], h[n + 2], h[n + 3]);
    sdtA[(size_t)(b * NCH + c) * DM + d] = sdt;
}

// ---------------- scan pass 2: sequential combine across chunks (in-place S -> start states H) ----------------
__global__ __launch_bounds__(256) void k_scan2(float* __restrict__ S,
    const float* __restrict__ sdtA, const float* __restrict__ alog)
{
    int t = blockIdx.x * 256 + threadIdx.x;           // over BATCH*DM*NS
    int n = t & (NS - 1);
    int d = (t >> 4) & (DM - 1);
    int b = t >> 14;
    float a2 = -__expf(alog[d * NS + n]) * LOG2E;
    float H = 0.f;
    for (int c = 0; c < NCH; c++) {
        size_t idx = (((size_t)(b * NCH + c) * DM) + d) * NS + n;
        float Sv = S[idx];
        float sd = sdtA[(size_t)(b * NCH + c) * DM + d];
        S[idx] = H;                                   // start state of chunk c
        H = fmaf(fexp2(a2 * sd), H, Sv);
    }
}

// ---------------- scan pass 3: re-run chunks from true start state, emit y ----------------
__global__ __launch_bounds__(256) void k_scan3(const float* __restrict__ dt,
    const float* __restrict__ xc, const float* __restrict__ Bs,
    const float* __restrict__ Cs, const float* __restrict__ alog,
    const float* __restrict__ Dp, const float* __restrict__ S,
    float* __restrict__ out)
{
    int d = blockIdx.x * 256 + threadIdx.x;
    int c = blockIdx.y;
    int b = blockIdx.z;
    float a2[NS], h[NS];
    const float* hp = S + (((size_t)(b * NCH + c) * DM) + d) * NS;
    #pragma unroll
    for (int n = 0; n < NS; n++) {
        a2[n] = -__expf(alog[d * NS + n]) * LOG2E;
        h[n] = hp[n];
    }
    float dpv = Dp[d];
    int l0 = c * CL;
    const float* dtp = dt + ((size_t)(b * SEQ + l0)) * DM + d;
    const float* xcp = xc + ((size_t)(b * SEQ + l0)) * DM + d;
    const float* bp  = Bs + ((size_t)(b * SEQ + l0)) * NS;
    const float* cp  = Cs + ((size_t)(b * SEQ + l0)) * NS;
    float* op = out + ((size_t)(b * SEQ + l0)) * DM + d;
    #pragma unroll 2
    for (int i = 0; i < CL; i++) {
        float dtv = dtp[(size_t)i * DM];
        float xcv = xcp[(size_t)i * DM];
        float dbx = dtv * xcv;
        float y = 0.f;
        #pragma unroll
        for (int n = 0; n < NS; n++) {
            float e = fexp2(dtv * a2[n]);
            h[n] = fmaf(e, h[n], dbx * bp[i * NS + n]);
            y = fmaf(h[n], cp[i * NS + n], y);
        }
        op[(size_t)i * DM] = fmaf(dpv, xcv, y);
    }
}

extern "C" void kernel_launch(void* const* d_in, const int* in_sizes, int n_in,
                              void* d_out, int out_size, void* d_ws, size_t ws_size,
                              hipStream_t stream)
{
    const float* x    = (const float*)d_in[0];
    const float* cw   = (const float*)d_in[1];
    const float* cb   = (const float*)d_in[2];
    const float* wxp  = (const float*)d_in[3];
    const float* wdt  = (const float*)d_in[4];
    const float* bdt  = (const float*)d_in[5];
    const float* wb   = (const float*)d_in[6];
    const float* wc   = (const float*)d_in[7];
    const float* alog = (const float*)d_in[8];
    const float* dpar = (const float*)d_in[9];
    float* out = (float*)d_out;
    float* ws  = (float*)d_ws;

    // workspace layout (floats)
    float* xc = ws;                     // 4194304
    float* dt = ws + 4194304;           // 4194304
    float* dl = ws + 8388608;           // 262144
    float* Bs = ws + 8650752;           // 65536
    float* Cs = ws + 8716288;           // 65536
    float* S  = ws + 8781824;           // 4194304  (B*NCH*DM*NS)
    float* sd = ws + 12976128;          // 262144   (B*NCH*DM)
    float* wt = ws + 13238272;          // 65536    (RK*DM transposed)

    k_conv <<<dim3(BATCH * SEQ * DM / 256), dim3(256), 0, stream>>>(x, cw, cb, xc);
    k_twdt <<<dim3(RK * DM / 256),          dim3(256), 0, stream>>>(wdt, wt);
    k_proj <<<dim3(BATCH * SEQ),            dim3(256), 0, stream>>>(xc, wxp, wb, wc, dl, Bs, Cs);
    k_dt   <<<dim3(DM / 256, BATCH * SEQ / 16), dim3(256), 0, stream>>>(dl, wt, bdt, dt);
    k_scan1<<<dim3(DM / 256, NCH, BATCH),   dim3(256), 0, stream>>>(dt, xc, Bs, alog, S, sd);
    k_scan2<<<dim3(BATCH * DM * NS / 256),  dim3(256), 0, stream>>>(S, sd, alog);
    k_scan3<<<dim3(DM / 256, NCH, BATCH),   dim3(256), 0, stream>>>(dt, xc, Bs, Cs, alog, dpar, S, out);
}

// Round 2
// 166.650 us; speedup vs baseline: 1.2496x; 1.2496x over previous
//
#include <hip/hip_runtime.h>
#include <math.h>

#define BATCH 2
#define SEQ   2048
#define DM    1024
#define NS    16
#define RK    64
#define NCH   128            // chunks over SEQ
#define CL    (SEQ / NCH)    // 16 steps per chunk
#define NPROJ 96             // 64 dt_low + 16 B + 16 C

#define LOG2E 1.4426950408889634f

typedef __attribute__((ext_vector_type(8))) short bf16x8;   // 8 bf16 in 4 VGPRs
typedef __attribute__((ext_vector_type(4))) float f32x4;

#if __has_builtin(__builtin_amdgcn_exp2f)
__device__ __forceinline__ float fexp2(float x) { return __builtin_amdgcn_exp2f(x); }
#else
__device__ __forceinline__ float fexp2(float x) { return exp2f(x); }
#endif

__device__ __forceinline__ unsigned short f2bf(float f) {
    union { float f; unsigned int u; } v; v.f = f;
    unsigned int u = v.u;
    u += 0x7FFFu + ((u >> 16) & 1u);     // round-to-nearest-even
    return (unsigned short)(u >> 16);
}

// ---------------- conv (depthwise, causal, K=4) + SiLU; writes fp32 + bf16 copies ----
__global__ __launch_bounds__(256) void k_conv(const float* __restrict__ x,
    const float* __restrict__ cw, const float* __restrict__ cb,
    float* __restrict__ xc, unsigned short* __restrict__ xcb)
{
    int idx = blockIdx.x * 256 + threadIdx.x;        // over B*SEQ*DM
    int d = idx & (DM - 1);
    int l = (idx >> 10) & (SEQ - 1);
    float4 w = *(const float4*)(cw + d * 4);
    float acc = cb[d];
    float x0 = (l >= 3) ? x[idx - 3 * DM] : 0.f;
    float x1 = (l >= 2) ? x[idx - 2 * DM] : 0.f;
    float x2 = (l >= 1) ? x[idx - 1 * DM] : 0.f;
    float x3 = x[idx];
    acc = fmaf(x0, w.x, acc);
    acc = fmaf(x1, w.y, acc);
    acc = fmaf(x2, w.z, acc);
    acc = fmaf(x3, w.w, acc);
    float e = __expf(-acc);
    float s = acc / (1.f + e);
    xc[idx] = s;
    xcb[idx] = f2bf(s);
}

// ---------------- transpose dt_proj_w (DM x RK) -> (RK x DM) ----------------
__global__ __launch_bounds__(256) void k_twdt(const float* __restrict__ w,
                                              float* __restrict__ wt)
{
    int t = blockIdx.x * 256 + threadIdx.x;          // over RK*DM, out idx r*DM+d
    int d = t & (DM - 1);
    int r = t >> 10;
    wt[t] = w[d * RK + r];
}

// ---------------- pre-permute [Wdt;Wb;Wc] (96x1024) into MFMA B-fragment order ----
// wf[(((t*32)+s)*64 + lane)*8 + i] = bf16( W_all[t*16 + (lane&15)][s*32 + (lane>>4)*8 + i] )
__global__ __launch_bounds__(256) void k_wprep(const float* __restrict__ wx,
    const float* __restrict__ wb, const float* __restrict__ wc,
    unsigned short* __restrict__ wf)
{
    int idx = blockIdx.x * 256 + threadIdx.x;        // over 6*32*64*8 = 98304
    int i    = idx & 7;
    int lane = (idx >> 3) & 63;
    int s    = (idx >> 9) & 31;
    int t    = idx >> 14;
    int j = t * 16 + (lane & 15);
    int k = s * 32 + ((lane >> 4) << 3) + i;
    float v = (j < 64) ? wx[(size_t)j * DM + k]
            : (j < 80) ? wb[(size_t)(j - 64) * DM + k]
                       : wc[(size_t)(j - 80) * DM + k];
    wf[idx] = f2bf(v);
}

// ---------------- fused projections via MFMA: C[4096][96] = xc @ W_all^T -----------
// one wave per 16-row stripe; 6 16x16 accumulator tiles cover the 96 columns
__global__ __launch_bounds__(64) void k_proj(const unsigned short* __restrict__ xcb,
    const unsigned short* __restrict__ wf, float* __restrict__ dl,
    float* __restrict__ Bs, float* __restrict__ Cs)
{
    int lane = threadIdx.x;
    int r0 = blockIdx.x * 16;
    int m = lane & 15, q = lane >> 4;
    f32x4 acc[6];
    #pragma unroll
    for (int t = 0; t < 6; t++) acc[t] = (f32x4){0.f, 0.f, 0.f, 0.f};

    const unsigned short* ap = xcb + (size_t)(r0 + m) * DM + q * 8;
    #pragma unroll 4
    for (int s = 0; s < 32; s++) {
        bf16x8 a = *(const bf16x8*)(ap + s * 32);
        #pragma unroll
        for (int t = 0; t < 6; t++) {
            bf16x8 b = *(const bf16x8*)(wf + (size_t)((t * 32 + s) * 64 + lane) * 8);
            acc[t] = __builtin_amdgcn_mfma_f32_16x16x32_bf16(a, b, acc[t], 0, 0, 0);
        }
    }
    #pragma unroll
    for (int t = 0; t < 6; t++) {
        #pragma unroll
        for (int i = 0; i < 4; i++) {
            int row = r0 + q * 4 + i;                 // C/D: row = quad*4+reg
            int col = t * 16 + m;                     //      col = lane&15
            float v = acc[t][i];
            if (col < 64)      dl[(size_t)row * RK + col] = v;
            else if (col < 80) Bs[(size_t)row * NS + (col - 64)] = v;
            else               Cs[(size_t)row * NS + (col - 80)] = v;
        }
    }
}

// ---------------- dt = softplus(dl(4096x64) @ WdtT + b); 4 cols/thread ------------
__global__ __launch_bounds__(256) void k_dt(const float* __restrict__ dl,
    const float* __restrict__ wt, const float* __restrict__ bias,
    float* __restrict__ dt)
{
    __shared__ __align__(16) float lr[16][RK];
    int tid = threadIdx.x;
    int row0 = blockIdx.x * 16;
    ((float4*)&lr[0][0])[tid] = ((const float4*)(dl + (size_t)row0 * RK))[tid];
    __syncthreads();
    int d0 = tid * 4;
    float4 acc[16];
    #pragma unroll
    for (int mm = 0; mm < 16; mm++) acc[mm] = make_float4(0.f, 0.f, 0.f, 0.f);
    for (int r = 0; r < RK; r++) {
        float4 w = *(const float4*)(wt + (size_t)r * DM + d0);
        #pragma unroll
        for (int mm = 0; mm < 16; mm++) {
            float lv = lr[mm][r];
            acc[mm].x = fmaf(lv, w.x, acc[mm].x);
            acc[mm].y = fmaf(lv, w.y, acc[mm].y);
            acc[mm].z = fmaf(lv, w.z, acc[mm].z);
            acc[mm].w = fmaf(lv, w.w, acc[mm].w);
        }
    }
    float4 b = *(const float4*)(bias + d0);
    #pragma unroll
    for (int mm = 0; mm < 16; mm++) {
        float4 z = make_float4(acc[mm].x + b.x, acc[mm].y + b.y,
                               acc[mm].z + b.z, acc[mm].w + b.w);
        float4 o;
        o.x = fmaxf(z.x, 0.f) + __logf(1.f + __expf(-fabsf(z.x)));
        o.y = fmaxf(z.y, 0.f) + __logf(1.f + __expf(-fabsf(z.y)));
        o.z = fmaxf(z.z, 0.f) + __logf(1.f + __expf(-fabsf(z.z)));
        o.w = fmaxf(z.w, 0.f) + __logf(1.f + __expf(-fabsf(z.w)));
        *(float4*)(dt + (size_t)(row0 + mm) * DM + d0) = o;
    }
}

// ---------------- scan pass 1: chunk-local states + sum(dt) per chunk ----------------
__global__ __launch_bounds__(256) void k_scan1(const float* __restrict__ dt,
    const float* __restrict__ xc, const float* __restrict__ Bs,
    const float* __restrict__ alog, float* __restrict__ S,
    float* __restrict__ sdtA)
{
    int d = blockIdx.x * 256 + threadIdx.x;
    int c = blockIdx.y;
    int b = blockIdx.z;
    float a2[NS], h[NS];
    #pragma unroll
    for (int n = 0; n < NS; n++) {
        a2[n] = -__expf(alog[d * NS + n]) * LOG2E;
        h[n] = 0.f;
    }
    int l0 = c * CL;
    const float* dtp = dt + ((size_t)(b * SEQ + l0)) * DM + d;
    const float* xcp = xc + ((size_t)(b * SEQ + l0)) * DM + d;
    const float* bp  = Bs + ((size_t)(b * SEQ + l0)) * NS;
    float sdt = 0.f;
    #pragma unroll 4
    for (int i = 0; i < CL; i++) {
        float dtv = dtp[(size_t)i * DM];
        float xcv = xcp[(size_t)i * DM];
        float dbx = dtv * xcv;
        sdt += dtv;
        #pragma unroll
        for (int n = 0; n < NS; n++) {
            float e = fexp2(dtv * a2[n]);
            h[n] = fmaf(e, h[n], dbx * bp[i * NS + n]);
        }
    }
    float* sp = S + (((size_t)(b * NCH + c) * DM) + d) * NS;
    #pragma unroll
    for (int n = 0; n < NS; n += 4)
        *(float4*)(sp + n) = make_float4(h[n], h[n + 1], h[n + 2], h[n + 3]);
    sdtA[(size_t)(b * NCH + c) * DM + d] = sdt;
}

// ---------------- scan pass 2: sequential combine across chunks (in-place S -> start states H) ----------------
__global__ __launch_bounds__(256) void k_scan2(float* __restrict__ S,
    const float* __restrict__ sdtA, const float* __restrict__ alog)
{
    int t = blockIdx.x * 256 + threadIdx.x;           // over BATCH*DM*NS
    int n = t & (NS - 1);
    int d = (t >> 4) & (DM - 1);
    int b = t >> 14;
    float a2 = -__expf(alog[d * NS + n]) * LOG2E;
    float H = 0.f;
    for (int c = 0; c < NCH; c++) {
        size_t idx = (((size_t)(b * NCH + c) * DM) + d) * NS + n;
        float Sv = S[idx];
        float sd = sdtA[(size_t)(b * NCH + c) * DM + d];
        S[idx] = H;                                   // start state of chunk c
        H = fmaf(fexp2(a2 * sd), H, Sv);
    }
}

// ---------------- scan pass 3: re-run chunks from true start state, emit y ----------------
__global__ __launch_bounds__(256) void k_scan3(const float* __restrict__ dt,
    const float* __restrict__ xc, const float* __restrict__ Bs,
    const float* __restrict__ Cs, const float* __restrict__ alog,
    const float* __restrict__ Dp, const float* __restrict__ S,
    float* __restrict__ out)
{
    int d = blockIdx.x * 256 + threadIdx.x;
    int c = blockIdx.y;
    int b = blockIdx.z;
    float a2[NS], h[NS];
    const float* hp = S + (((size_t)(b * NCH + c) * DM) + d) * NS;
    #pragma unroll
    for (int n = 0; n < NS; n++) {
        a2[n] = -__expf(alog[d * NS + n]) * LOG2E;
        h[n] = hp[n];
    }
    float dpv = Dp[d];
    int l0 = c * CL;
    const float* dtp = dt + ((size_t)(b * SEQ + l0)) * DM + d;
    const float* xcp = xc + ((size_t)(b * SEQ + l0)) * DM + d;
    const float* bp  = Bs + ((size_t)(b * SEQ + l0)) * NS;
    const float* cp  = Cs + ((size_t)(b * SEQ + l0)) * NS;
    float* op = out + ((size_t)(b * SEQ + l0)) * DM + d;
    #pragma unroll 2
    for (int i = 0; i < CL; i++) {
        float dtv = dtp[(size_t)i * DM];
        float xcv = xcp[(size_t)i * DM];
        float dbx = dtv * xcv;
        float y = 0.f;
        #pragma unroll
        for (int n = 0; n < NS; n++) {
            float e = fexp2(dtv * a2[n]);
            h[n] = fmaf(e, h[n], dbx * bp[i * NS + n]);
            y = fmaf(h[n], cp[i * NS + n], y);
        }
        op[(size_t)i * DM] = fmaf(dpv, xcv, y);
    }
}

extern "C" void kernel_launch(void* const* d_in, const int* in_sizes, int n_in,
                              void* d_out, int out_size, void* d_ws, size_t ws_size,
                              hipStream_t stream)
{
    const float* x    = (const float*)d_in[0];
    const float* cw   = (const float*)d_in[1];
    const float* cb   = (const float*)d_in[2];
    const float* wxp  = (const float*)d_in[3];
    const float* wdt  = (const float*)d_in[4];
    const float* bdt  = (const float*)d_in[5];
    const float* wb   = (const float*)d_in[6];
    const float* wc   = (const float*)d_in[7];
    const float* alog = (const float*)d_in[8];
    const float* dpar = (const float*)d_in[9];
    float* out = (float*)d_out;
    float* ws  = (float*)d_ws;

    // workspace layout (floats)
    float* xc = ws;                     // 4194304
    float* dt = ws + 4194304;           // 4194304
    float* dl = ws + 8388608;           // 262144
    float* Bs = ws + 8650752;           // 65536
    float* Cs = ws + 8716288;           // 65536
    float* S  = ws + 8781824;           // 4194304  (B*NCH*DM*NS)
    float* sd = ws + 12976128;          // 262144   (B*NCH*DM)
    float* wt = ws + 13238272;          // 65536    (RK*DM transposed)
    unsigned short* wf = (unsigned short*)(ws + 13303808);  // 98304 bf16 (48 KB region)
    // xcb16 aliases S: xcb16 live conv->proj; S written first in scan1 (after proj)
    unsigned short* xcb = (unsigned short*)S;               // 4194304 bf16 = 8 MB

    k_conv <<<dim3(BATCH * SEQ * DM / 256), dim3(256), 0, stream>>>(x, cw, cb, xc, xcb);
    k_twdt <<<dim3(RK * DM / 256),          dim3(256), 0, stream>>>(wdt, wt);
    k_wprep<<<dim3(NPROJ * DM / 256),       dim3(256), 0, stream>>>(wxp, wb, wc, wf);
    k_proj <<<dim3(BATCH * SEQ / 16),       dim3(64),  0, stream>>>(xcb, wf, dl, Bs, Cs);
    k_dt   <<<dim3(BATCH * SEQ / 16),       dim3(256), 0, stream>>>(dl, wt, bdt, dt);
    k_scan1<<<dim3(DM / 256, NCH, BATCH),   dim3(256), 0, stream>>>(dt, xc, Bs, alog, S, sd);
    k_scan2<<<dim3(BATCH * DM * NS / 256),  dim3(256), 0, stream>>>(S, sd, alog);
    k_scan3<<<dim3(DM / 256, NCH, BATCH),   dim3(256), 0, stream>>>(dt, xc, Bs, Cs, alog, dpar, S, out);
}

// Round 3
// 163.376 us; speedup vs baseline: 1.2747x; 1.0200x over previous
//
#include <hip/hip_runtime.h>
#include <math.h>

#define BATCH 2
#define SEQ   2048
#define DM    1024
#define NS    16
#define RK    64
#define NCH   128            // chunks over SEQ
#define CL    (SEQ / NCH)    // 16 steps per chunk
#define NGRP  8              // groups of 16 chunks (two-level combine)
#define GC    16             // chunks per group
#define NPROJ 96             // 64 dt_low + 16 B + 16 C

#define LOG2E 1.4426950408889634f

typedef __attribute__((ext_vector_type(8))) short bf16x8;   // 8 bf16 in 4 VGPRs
typedef __attribute__((ext_vector_type(4))) float f32x4;

#if __has_builtin(__builtin_amdgcn_exp2f)
__device__ __forceinline__ float fexp2(float x) { return __builtin_amdgcn_exp2f(x); }
#else
__device__ __forceinline__ float fexp2(float x) { return exp2f(x); }
#endif

__device__ __forceinline__ unsigned short f2bf(float f) {
    union { float f; unsigned int u; } v; v.f = f;
    unsigned int u = v.u;
    u += 0x7FFFu + ((u >> 16) & 1u);     // round-to-nearest-even
    return (unsigned short)(u >> 16);
}
__device__ __forceinline__ float bf2f(unsigned short s) {
    union { unsigned int u; float f; } v; v.u = ((unsigned int)s) << 16;
    return v.f;
}

// ---------------- conv (depthwise, causal, K=4) + SiLU -> bf16 ----------------
__global__ __launch_bounds__(256) void k_conv(const float* __restrict__ x,
    const float* __restrict__ cw, const float* __restrict__ cb,
    unsigned short* __restrict__ xcb)
{
    int idx = blockIdx.x * 256 + threadIdx.x;        // over B*SEQ*DM
    int d = idx & (DM - 1);
    int l = (idx >> 10) & (SEQ - 1);
    float4 w = *(const float4*)(cw + d * 4);
    float acc = cb[d];
    float x0 = (l >= 3) ? x[idx - 3 * DM] : 0.f;
    float x1 = (l >= 2) ? x[idx - 2 * DM] : 0.f;
    float x2 = (l >= 1) ? x[idx - 1 * DM] : 0.f;
    float x3 = x[idx];
    acc = fmaf(x0, w.x, acc);
    acc = fmaf(x1, w.y, acc);
    acc = fmaf(x2, w.z, acc);
    acc = fmaf(x3, w.w, acc);
    float e = __expf(-acc);
    float s = acc / (1.f + e);
    xcb[idx] = f2bf(s);
}

// ---------------- prep: transpose dt_proj_w + permute [Wdt;Wb;Wc] into B-frag order ----
__global__ __launch_bounds__(256) void k_prep(const float* __restrict__ w,
    float* __restrict__ wt, const float* __restrict__ wx,
    const float* __restrict__ wb, const float* __restrict__ wc,
    unsigned short* __restrict__ wf)
{
    int t = blockIdx.x * 256 + threadIdx.x;          // 0 .. 65536+98304
    if (t < RK * DM) {                               // transpose (DM x RK) -> (RK x DM)
        int d = t & (DM - 1);
        int r = t >> 10;
        wt[t] = w[d * RK + r];
    } else {
        int idx = t - RK * DM;                       // over 6*32*64*8 = 98304
        int i    = idx & 7;
        int lane = (idx >> 3) & 63;
        int s    = (idx >> 9) & 31;
        int tt   = idx >> 14;
        int j = tt * 16 + (lane & 15);
        int k = s * 32 + ((lane >> 4) << 3) + i;
        float v = (j < 64) ? wx[(size_t)j * DM + k]
                : (j < 80) ? wb[(size_t)(j - 64) * DM + k]
                           : wc[(size_t)(j - 80) * DM + k];
        wf[idx] = f2bf(v);
    }
}

// ---------------- fused projections via MFMA: C[4096][96] = xc @ W_all^T -----------
__global__ __launch_bounds__(64) void k_proj(const unsigned short* __restrict__ xcb,
    const unsigned short* __restrict__ wf, float* __restrict__ dl,
    float* __restrict__ Bs, float* __restrict__ Cs)
{
    int lane = threadIdx.x;
    int r0 = blockIdx.x * 16;
    int m = lane & 15, q = lane >> 4;
    f32x4 acc[6];
    #pragma unroll
    for (int t = 0; t < 6; t++) acc[t] = (f32x4){0.f, 0.f, 0.f, 0.f};

    const unsigned short* ap = xcb + (size_t)(r0 + m) * DM + q * 8;
    #pragma unroll 4
    for (int s = 0; s < 32; s++) {
        bf16x8 a = *(const bf16x8*)(ap + s * 32);
        #pragma unroll
        for (int t = 0; t < 6; t++) {
            bf16x8 b = *(const bf16x8*)(wf + (size_t)((t * 32 + s) * 64 + lane) * 8);
            acc[t] = __builtin_amdgcn_mfma_f32_16x16x32_bf16(a, b, acc[t], 0, 0, 0);
        }
    }
    #pragma unroll
    for (int t = 0; t < 6; t++) {
        #pragma unroll
        for (int i = 0; i < 4; i++) {
            int row = r0 + q * 4 + i;                 // C/D: row = quad*4+reg
            int col = t * 16 + m;                     //      col = lane&15
            float v = acc[t][i];
            if (col < 64)      dl[(size_t)row * RK + col] = v;
            else if (col < 80) Bs[(size_t)row * NS + (col - 64)] = v;
            else               Cs[(size_t)row * NS + (col - 80)] = v;
        }
    }
}

// ---------------- dt = softplus(dl(4096x64) @ WdtT + b); 4 cols/thread ------------
__global__ __launch_bounds__(256) void k_dt(const float* __restrict__ dl,
    const float* __restrict__ wt, const float* __restrict__ bias,
    float* __restrict__ dt)
{
    __shared__ __align__(16) float lr[16][RK];
    int tid = threadIdx.x;
    int row0 = blockIdx.x * 16;
    ((float4*)&lr[0][0])[tid] = ((const float4*)(dl + (size_t)row0 * RK))[tid];
    __syncthreads();
    int d0 = tid * 4;
    float4 acc[16];
    #pragma unroll
    for (int mm = 0; mm < 16; mm++) acc[mm] = make_float4(0.f, 0.f, 0.f, 0.f);
    for (int r = 0; r < RK; r++) {
        float4 w = *(const float4*)(wt + (size_t)r * DM + d0);
        #pragma unroll
        for (int mm = 0; mm < 16; mm++) {
            float lv = lr[mm][r];
            acc[mm].x = fmaf(lv, w.x, acc[mm].x);
            acc[mm].y = fmaf(lv, w.y, acc[mm].y);
            acc[mm].z = fmaf(lv, w.z, acc[mm].z);
            acc[mm].w = fmaf(lv, w.w, acc[mm].w);
        }
    }
    float4 b = *(const float4*)(bias + d0);
    #pragma unroll
    for (int mm = 0; mm < 16; mm++) {
        float4 z = make_float4(acc[mm].x + b.x, acc[mm].y + b.y,
                               acc[mm].z + b.z, acc[mm].w + b.w);
        float4 o;
        o.x = fmaxf(z.x, 0.f) + __logf(1.f + __expf(-fabsf(z.x)));
        o.y = fmaxf(z.y, 0.f) + __logf(1.f + __expf(-fabsf(z.y)));
        o.z = fmaxf(z.z, 0.f) + __logf(1.f + __expf(-fabsf(z.z)));
        o.w = fmaxf(z.w, 0.f) + __logf(1.f + __expf(-fabsf(z.w)));
        *(float4*)(dt + (size_t)(row0 + mm) * DM + d0) = o;
    }
}

// ---------------- scan pass 1: chunk-local states + sum(dt) per chunk ----------------
__global__ __launch_bounds__(256) void k_scan1(const float* __restrict__ dt,
    const unsigned short* __restrict__ xcb, const float* __restrict__ Bs,
    const float* __restrict__ alog, float* __restrict__ S,
    float* __restrict__ sdtA)
{
    int d = blockIdx.x * 256 + threadIdx.x;
    int c = blockIdx.y;
    int b = blockIdx.z;
    float a2[NS], h[NS];
    #pragma unroll
    for (int n = 0; n < NS; n++) {
        a2[n] = -__expf(alog[d * NS + n]) * LOG2E;
        h[n] = 0.f;
    }
    int l0 = c * CL;
    const float* dtp = dt + ((size_t)(b * SEQ + l0)) * DM + d;
    const unsigned short* xcp = xcb + ((size_t)(b * SEQ + l0)) * DM + d;
    const float* bp  = Bs + ((size_t)(b * SEQ + l0)) * NS;
    float sdt = 0.f;
    #pragma unroll 4
    for (int i = 0; i < CL; i++) {
        float dtv = dtp[(size_t)i * DM];
        float xcv = bf2f(xcp[(size_t)i * DM]);
        float dbx = dtv * xcv;
        sdt += dtv;
        #pragma unroll
        for (int n = 0; n < NS; n++) {
            float e = fexp2(dtv * a2[n]);
            h[n] = fmaf(e, h[n], dbx * bp[i * NS + n]);
        }
    }
    float* sp = S + (((size_t)(b * NCH + c) * DM) + d) * NS;
    #pragma unroll
    for (int n = 0; n < NS; n += 4)
        *(float4*)(sp + n) = make_float4(h[n], h[n + 1], h[n + 2], h[n + 3]);
    sdtA[(size_t)(b * NCH + c) * DM + d] = sdt;
}

// ---------------- scan pass 2a: within-group combine (16 chunks), 16x parallelism ----
// t -> (b, g, d, n); rewrites S[c] to within-group chunk-start state, emits group
// end-state Gend, within-group cumulative-dt-before-chunk csd, and group total Gsd.
__global__ __launch_bounds__(256) void k_s2a(float* __restrict__ S,
    const float* __restrict__ sd, float* __restrict__ csd,
    float* __restrict__ Gend, float* __restrict__ Gsd,
    const float* __restrict__ alog)
{
    int t = blockIdx.x * 256 + threadIdx.x;           // over B*NGRP*DM*NS
    int n = t & (NS - 1);
    int d = (t >> 4) & (DM - 1);
    int g = (t >> 14) & (NGRP - 1);
    int b = t >> 17;
    float a2 = -__expf(alog[d * NS + n]) * LOG2E;
    float H = 0.f, cum = 0.f;
    int c0 = g * GC;
    #pragma unroll
    for (int i = 0; i < GC; i++) {
        int c = c0 + i;
        size_t sidx = (((size_t)(b * NCH + c) * DM) + d) * NS + n;
        size_t didx = (size_t)(b * NCH + c) * DM + d;
        float Sv = S[sidx];
        float sdv = sd[didx];
        S[sidx] = H;                                  // within-group start state
        H = fmaf(fexp2(a2 * sdv), H, Sv);
        if (n == 0) csd[didx] = cum;                  // cum dt before chunk c (in group)
        cum += sdv;
    }
    Gend[t] = H;
    if (n == 0) Gsd[(size_t)(b * NGRP + g) * DM + d] = cum;
}

// ---------------- scan pass 2b: combine the 8 groups (tiny, L2-resident) ------------
__global__ __launch_bounds__(256) void k_s2b(const float* __restrict__ Gend,
    const float* __restrict__ Gsd, const float* __restrict__ alog,
    float* __restrict__ Gstart)
{
    int t = blockIdx.x * 256 + threadIdx.x;           // over B*DM*NS
    int n = t & (NS - 1);
    int d = (t >> 4) & (DM - 1);
    int b = t >> 14;
    float a2 = -__expf(alog[d * NS + n]) * LOG2E;
    float H = 0.f;
    #pragma unroll
    for (int g = 0; g < NGRP; g++) {
        size_t gi = (((size_t)(b * NGRP + g) * DM) + d) * NS + n;
        float Gv = Gend[gi];
        float sdv = Gsd[(size_t)(b * NGRP + g) * DM + d];
        Gstart[gi] = H;                               // true start state of group g
        H = fmaf(fexp2(a2 * sdv), H, Gv);
    }
}

// ---------------- scan pass 3: re-run chunks from true start state, emit y ----------
__global__ __launch_bounds__(256) void k_scan3(const float* __restrict__ dt,
    const unsigned short* __restrict__ xcb, const float* __restrict__ Bs,
    const float* __restrict__ Cs, const float* __restrict__ alog,
    const float* __restrict__ Dp, const float* __restrict__ S,
    const float* __restrict__ csd, const float* __restrict__ Gstart,
    float* __restrict__ out)
{
    int d = blockIdx.x * 256 + threadIdx.x;
    int c = blockIdx.y;
    int b = blockIdx.z;
    int g = c >> 4;
    float a2[NS], h[NS];
    const float* sp = S + (((size_t)(b * NCH + c) * DM) + d) * NS;
    const float* gp = Gstart + (((size_t)(b * NGRP + g) * DM) + d) * NS;
    float cum = csd[(size_t)(b * NCH + c) * DM + d];
    #pragma unroll
    for (int n = 0; n < NS; n++) {
        a2[n] = -__expf(alog[d * NS + n]) * LOG2E;
        // true chunk-start state: within-group start + decayed group start
        h[n] = fmaf(fexp2(a2[n] * cum), gp[n], sp[n]);
    }
    float dpv = Dp[d];
    int l0 = c * CL;
    const float* dtp = dt + ((size_t)(b * SEQ + l0)) * DM + d;
    const unsigned short* xcp = xcb + ((size_t)(b * SEQ + l0)) * DM + d;
    const float* bp  = Bs + ((size_t)(b * SEQ + l0)) * NS;
    const float* cp  = Cs + ((size_t)(b * SEQ + l0)) * NS;
    float* op = out + ((size_t)(b * SEQ + l0)) * DM + d;
    #pragma unroll 2
    for (int i = 0; i < CL; i++) {
        float dtv = dtp[(size_t)i * DM];
        float xcv = bf2f(xcp[(size_t)i * DM]);
        float dbx = dtv * xcv;
        float y = 0.f;
        #pragma unroll
        for (int n = 0; n < NS; n++) {
            float e = fexp2(dtv * a2[n]);
            h[n] = fmaf(e, h[n], dbx * bp[i * NS + n]);
            y = fmaf(h[n], cp[i * NS + n], y);
        }
        op[(size_t)i * DM] = fmaf(dpv, xcv, y);
    }
}

extern "C" void kernel_launch(void* const* d_in, const int* in_sizes, int n_in,
                              void* d_out, int out_size, void* d_ws, size_t ws_size,
                              hipStream_t stream)
{
    const float* x    = (const float*)d_in[0];
    const float* cw   = (const float*)d_in[1];
    const float* cb   = (const float*)d_in[2];
    const float* wxp  = (const float*)d_in[3];
    const float* wdt  = (const float*)d_in[4];
    const float* bdt  = (const float*)d_in[5];
    const float* wb   = (const float*)d_in[6];
    const float* wc   = (const float*)d_in[7];
    const float* alog = (const float*)d_in[8];
    const float* dpar = (const float*)d_in[9];
    float* out = (float*)d_out;
    float* ws  = (float*)d_ws;

    // workspace layout (float offsets)
    float* dt   = ws;                        // 4194304
    float* dl   = ws + 4194304;              // 262144
    float* Bs   = ws + 4456448;              // 65536
    float* Cs   = ws + 4521984;              // 65536
    float* S    = ws + 4587520;              // 4194304 (B*NCH*DM*NS)
    float* sd   = ws + 8781824;              // 262144  (B*NCH*DM)
    float* csd  = ws + 9043968;              // 262144
    float* wt   = ws + 9306112;              // 65536   (RK x DM transposed)
    float* Gend = ws + 9371648;              // 262144  (B*NGRP*DM*NS)
    float* Gst  = ws + 9633792;              // 262144
    float* Gsd  = ws + 9895936;              // 16384   (B*NGRP*DM)
    unsigned short* wf  = (unsigned short*)(ws + 9912320);   // 98304 bf16
    unsigned short* xcb = (unsigned short*)(ws + 9961472);   // 4194304 bf16

    k_conv <<<dim3(BATCH * SEQ * DM / 256),        dim3(256), 0, stream>>>(x, cw, cb, xcb);
    k_prep <<<dim3((RK * DM + NPROJ * DM) / 256),  dim3(256), 0, stream>>>(wdt, wt, wxp, wb, wc, wf);
    k_proj <<<dim3(BATCH * SEQ / 16),              dim3(64),  0, stream>>>(xcb, wf, dl, Bs, Cs);
    k_dt   <<<dim3(BATCH * SEQ / 16),              dim3(256), 0, stream>>>(dl, wt, bdt, dt);
    k_scan1<<<dim3(DM / 256, NCH, BATCH),          dim3(256), 0, stream>>>(dt, xcb, Bs, alog, S, sd);
    k_s2a  <<<dim3(BATCH * NGRP * DM * NS / 256),  dim3(256), 0, stream>>>(S, sd, csd, Gend, Gsd, alog);
    k_s2b  <<<dim3(BATCH * DM * NS / 256),         dim3(256), 0, stream>>>(Gend, Gsd, alog, Gst);
    k_scan3<<<dim3(DM / 256, NCH, BATCH),          dim3(256), 0, stream>>>(dt, xcb, Bs, Cs, alog, dpar, S, csd, Gst, out);
}